// Round 10
// baseline (203.458 us; speedup 1.0000x reference)
//
#include <hip/hip_runtime.h>
#include <math.h>

#define NN 1024
#define IN_DIM 64
#define H 128
#define NL 4
#define HEADS 4
#define DH 32
#define KSPLIT 8   // attention j-chunks of 128

// ---------------- embed (R3 form): h=relu(LN(x@embW+b)); aM=h@W1a+eb1; bM=h@W1b; g0=h@gcW0
// + in_proj/out_proj transposes as side work
__global__ __launch_bounds__(128) void k_embed(const float* __restrict__ x,
        const float* __restrict__ embW, const float* __restrict__ embB,
        const float* __restrict__ lng, const float* __restrict__ lnb,
        const float* __restrict__ eW1, const float* __restrict__ eb1,
        const float* __restrict__ gcW0,
        const float* __restrict__ inW, const float* __restrict__ outW,
        float* __restrict__ Wt_in, float* __restrict__ Wt_out,
        float* __restrict__ aM, float* __restrict__ bM, float* __restrict__ g0) {
    __shared__ float xs[IN_DIM];
    __shared__ float hs[H];
    __shared__ float red[H];
    int i = blockIdx.x, t = threadIdx.x;
    int gidx = i * 128 + t;
    if (gidx < 49152) {
        Wt_in[gidx] = inW[(gidx % 384) * 128 + gidx / 384];
    } else if (gidx < 65536) {
        int i2 = gidx - 49152;
        Wt_out[i2] = outW[(i2 % 128) * 128 + i2 / 128];
    }
    if (t < IN_DIM) xs[t] = x[i * IN_DIM + t];
    __syncthreads();
    float acc = embB[t];
    #pragma unroll 8
    for (int k = 0; k < IN_DIM; ++k) acc = fmaf(xs[k], embW[k * H + t], acc);
    red[t] = acc; __syncthreads();
    for (int s = 64; s > 0; s >>= 1) { if (t < s) red[t] += red[t + s]; __syncthreads(); }
    float mu = red[0] * (1.f / H);
    __syncthreads();
    float d = acc - mu;
    red[t] = d * d; __syncthreads();
    for (int s = 64; s > 0; s >>= 1) { if (t < s) red[t] += red[t + s]; __syncthreads(); }
    float var = red[0] * (1.f / H);
    float hv = d * rsqrtf(var + 1e-5f) * lng[t] + lnb[t];
    hv = fmaxf(hv, 0.f);
    hs[t] = hv;
    __syncthreads();
    float aa = eb1[t], bb = 0.f, gg = 0.f;
    #pragma unroll 8
    for (int k = 0; k < H; ++k) {
        float hk = hs[k];
        aa = fmaf(hk, eW1[k * H + t], aa);
        bb = fmaf(hk, eW1[(H + k) * H + t], bb);
        gg = fmaf(hk, gcW0[k * H + t], gg);
    }
    aM[i * H + t] = aa;
    bM[i * H + t] = bb;
    g0[i * H + t] = gg;
}

// ---------------- adj (R3 form): 32x32 tile, b transposed in LDS, float4 inner
#define AT 32
__global__ __launch_bounds__(256) void k_adj(const float* __restrict__ aM, const float* __restrict__ bM,
        const float* __restrict__ w2, const float* __restrict__ eb2p, float* __restrict__ adj) {
    __shared__ float as_[AT][H + 4];
    __shared__ float bst[H][AT + 4];
    __shared__ float w2s[H];
    int i0 = blockIdx.y * AT, j0 = blockIdx.x * AT;
    int t = threadIdx.x;
    for (int idx = t; idx < AT * H; idx += 256) {
        int r = idx >> 7, c = idx & 127;
        as_[r][c] = aM[(i0 + r) * H + c];
        bst[c][r] = bM[(j0 + r) * H + c];
    }
    if (t < H) w2s[t] = w2[t];
    __syncthreads();
    int ti = t >> 3, tjg = t & 7;
    float a0 = 0.f, a1 = 0.f, a2 = 0.f, a3 = 0.f;
    const float eb2 = eb2p[0];
    #pragma unroll 4
    for (int h = 0; h < H; ++h) {
        float av = as_[ti][h];
        float4 bv = *(const float4*)&bst[h][tjg * 4];
        float wh = w2s[h];
        a0 = fmaf(fmaxf(av + bv.x, 0.f), wh, a0);
        a1 = fmaf(fmaxf(av + bv.y, 0.f), wh, a1);
        a2 = fmaf(fmaxf(av + bv.z, 0.f), wh, a2);
        a3 = fmaf(fmaxf(av + bv.w, 0.f), wh, a3);
    }
    int i = i0 + ti, jb = j0 + tjg * 4;
    float4 ov;
    ov.x = (i == jb + 0) ? 0.f : 1.f / (1.f + __expf(-(a0 + eb2)));
    ov.y = (i == jb + 1) ? 0.f : 1.f / (1.f + __expf(-(a1 + eb2)));
    ov.z = (i == jb + 2) ? 0.f : 1.f / (1.f + __expf(-(a2 + eb2)));
    ov.w = (i == jb + 3) ? 0.f : 1.f / (1.f + __expf(-(a3 + eb2)));
    *(float4*)&adj[(size_t)i * NN + jb] = ov;
}

// ---------------- fused gc layer: gout = (adj @ g + bias) @ W  (no split-K, no partials)
// block = 4 rows x full j; 256 blocks x 512 thr
__global__ __launch_bounds__(512) void k_gc128(const float* __restrict__ adj,
        const float* __restrict__ g, const float* __restrict__ bias,
        const float* __restrict__ W, float* __restrict__ gout) {
    __shared__ float adjs[4][NN];    // 16 KB
    __shared__ float s[4][H];
    int B = blockIdx.x, T = threadIdx.x;
    int r0 = B * 4;
    #pragma unroll
    for (int it = 0; it < 2; ++it) {
        int idx = T + it * 512;            // [0,1024): 256 float4 per row
        int r = idx >> 8, jf = idx & 255;
        float4 v = *(const float4*)&adj[(size_t)(r0 + r) * NN + jf * 4];
        adjs[r][jf * 4 + 0] = v.x; adjs[r][jf * 4 + 1] = v.y;
        adjs[r][jf * 4 + 2] = v.z; adjs[r][jf * 4 + 3] = v.w;
    }
    __syncthreads();
    int rg = T >> 7, c = T & 127;
    float a0 = 0.f, a1 = 0.f, a2 = 0.f, a3 = 0.f;
    #pragma unroll 4
    for (int j = 0; j < NN; j += 4) {
        float g0 = g[(j + 0) * H + c];
        float g1 = g[(j + 1) * H + c];
        float g2 = g[(j + 2) * H + c];
        float g3 = g[(j + 3) * H + c];
        a0 = fmaf(adjs[rg][j + 0], g0, a0);
        a1 = fmaf(adjs[rg][j + 1], g1, a1);
        a2 = fmaf(adjs[rg][j + 2], g2, a2);
        a3 = fmaf(adjs[rg][j + 3], g3, a3);
    }
    s[rg][c] = (a0 + a1) + (a2 + a3) + bias[c];
    __syncthreads();
    float acc = 0.f;
    #pragma unroll 8
    for (int k = 0; k < H; ++k) acc = fmaf(s[rg][k], W[k * H + c], acc);
    gout[(r0 + rg) * H + c] = acc;
}

// same, but epilogue projects to qkv (H -> 384) with in_proj bias
__global__ __launch_bounds__(512) void k_gc384(const float* __restrict__ adj,
        const float* __restrict__ g, const float* __restrict__ bias,
        const float* __restrict__ Wt_in, const float* __restrict__ bias2,
        float* __restrict__ qkv) {
    __shared__ float adjs[4][NN];
    __shared__ float s[4][H];
    int B = blockIdx.x, T = threadIdx.x;
    int r0 = B * 4;
    #pragma unroll
    for (int it = 0; it < 2; ++it) {
        int idx = T + it * 512;
        int r = idx >> 8, jf = idx & 255;
        float4 v = *(const float4*)&adj[(size_t)(r0 + r) * NN + jf * 4];
        adjs[r][jf * 4 + 0] = v.x; adjs[r][jf * 4 + 1] = v.y;
        adjs[r][jf * 4 + 2] = v.z; adjs[r][jf * 4 + 3] = v.w;
    }
    __syncthreads();
    int rg = T >> 7, c = T & 127;
    float a0 = 0.f, a1 = 0.f, a2 = 0.f, a3 = 0.f;
    #pragma unroll 4
    for (int j = 0; j < NN; j += 4) {
        float g0 = g[(j + 0) * H + c];
        float g1 = g[(j + 1) * H + c];
        float g2 = g[(j + 2) * H + c];
        float g3 = g[(j + 3) * H + c];
        a0 = fmaf(adjs[rg][j + 0], g0, a0);
        a1 = fmaf(adjs[rg][j + 1], g1, a1);
        a2 = fmaf(adjs[rg][j + 2], g2, a2);
        a3 = fmaf(adjs[rg][j + 3], g3, a3);
    }
    s[rg][c] = (a0 + a1) + (a2 + a3) + bias[c];
    __syncthreads();
    #pragma unroll
    for (int rep = 0; rep < 3; ++rep) {
        int cc = c + rep * 128;
        float acc = bias2[cc];
        #pragma unroll 8
        for (int k = 0; k < H; ++k) acc = fmaf(s[rg][k], Wt_in[k * 384 + cc], acc);
        qkv[(r0 + rg) * 384 + cc] = acc;
    }
}

// ---------------- split-K attention (verbatim R3) + pp zeroing side-task
__global__ __launch_bounds__(256) void k_attn_part(const float* __restrict__ qkv,
        float* __restrict__ opart, float* __restrict__ mpart, float* __restrict__ lpart,
        float* __restrict__ pp) {
    __shared__ float kob[4][32][36];   // phase1: kT[32][132]; phase2: obuf
    __shared__ float qT[32][36];
    __shared__ float pT[128][36];
    __shared__ float marr[32], larr[32];
    float* kT = &kob[0][0][0];
    const int t = threadIdx.x;
    const int head = blockIdx.y, kp = blockIdx.z;
    const int i0 = blockIdx.x * 32, j0 = kp * 128;
    const int qoff = head * DH, koff = H + head * DH, voff = 2 * H + head * DH;
    const float scale = 0.17677669529663687f; // 1/sqrt(32)
    if (head == 0 && kp == 0 && t < 128) pp[blockIdx.x * 128 + t] = 0.f;  // zero pool accum
    {
        int qi = t >> 3, dg = t & 7;
        float4 qv = *(const float4*)&qkv[(i0 + qi) * 384 + qoff + dg * 4];
        qT[dg * 4 + 0][qi] = qv.x * scale;
        qT[dg * 4 + 1][qi] = qv.y * scale;
        qT[dg * 4 + 2][qi] = qv.z * scale;
        qT[dg * 4 + 3][qi] = qv.w * scale;
    }
    #pragma unroll
    for (int it = 0; it < 4; ++it) {
        int idx = t + it * 256;
        int j = idx >> 3, dg = idx & 7;
        float4 kv = *(const float4*)&qkv[(j0 + j) * 384 + koff + dg * 4];
        kT[(dg * 4 + 0) * 132 + j] = kv.x;
        kT[(dg * 4 + 1) * 132 + j] = kv.y;
        kT[(dg * 4 + 2) * 132 + j] = kv.z;
        kT[(dg * 4 + 3) * 132 + j] = kv.w;
    }
    __syncthreads();
    const int tq = t >> 5, tj = t & 31;
    float s[4][4] = {};
    #pragma unroll
    for (int kk = 0; kk < DH; ++kk) {
        float qa[4], ka[4];
        *(float4*)qa = *(float4*)&qT[kk][tq * 4];
        *(float4*)ka = *(float4*)&kT[kk * 132 + tj * 4];
        #pragma unroll
        for (int a = 0; a < 4; ++a)
            #pragma unroll
            for (int b = 0; b < 4; ++b) s[a][b] = fmaf(qa[a], ka[b], s[a][b]);
    }
    #pragma unroll
    for (int a = 0; a < 4; ++a) {
        float mm = fmaxf(fmaxf(s[a][0], s[a][1]), fmaxf(s[a][2], s[a][3]));
        #pragma unroll
        for (int off = 16; off > 0; off >>= 1) mm = fmaxf(mm, __shfl_xor(mm, off));
        float ll = 0.f;
        #pragma unroll
        for (int b = 0; b < 4; ++b) { s[a][b] = __expf(s[a][b] - mm); ll += s[a][b]; }
        #pragma unroll
        for (int off = 16; off > 0; off >>= 1) ll += __shfl_xor(ll, off);
        if (tj == 0) { marr[tq * 4 + a] = mm; larr[tq * 4 + a] = ll; }
    }
    #pragma unroll
    for (int b = 0; b < 4; ++b)
        #pragma unroll
        for (int a = 0; a < 4; ++a) pT[tj * 4 + b][tq * 4 + a] = s[a][b];
    __syncthreads();
    const int qg = t >> 5, dg2 = (t >> 2) & 7, st = t & 3;
    float o[4][4] = {};
    #pragma unroll 4
    for (int jj = 0; jj < 32; ++jj) {
        int j = st * 32 + jj;
        float pa[4], va[4];
        *(float4*)pa = *(float4*)&pT[j][qg * 4];
        *(float4*)va = *(const float4*)&qkv[(j0 + j) * 384 + voff + dg2 * 4];
        #pragma unroll
        for (int a = 0; a < 4; ++a)
            #pragma unroll
            for (int b = 0; b < 4; ++b) o[a][b] = fmaf(pa[a], va[b], o[a][b]);
    }
    __syncthreads();
    #pragma unroll
    for (int a = 0; a < 4; ++a)
        #pragma unroll
        for (int b = 0; b < 4; ++b) kob[st][qg * 4 + a][dg2 * 4 + b] = o[a][b];
    __syncthreads();
    {
        int q = t >> 3, d0 = (t & 7) * 4;
        float r0[4], r1[4], r2[4], r3[4];
        *(float4*)r0 = *(float4*)&kob[0][q][d0];
        *(float4*)r1 = *(float4*)&kob[1][q][d0];
        *(float4*)r2 = *(float4*)&kob[2][q][d0];
        *(float4*)r3 = *(float4*)&kob[3][q][d0];
        float4 ov;
        ov.x = (r0[0] + r1[0]) + (r2[0] + r3[0]);
        ov.y = (r0[1] + r1[1]) + (r2[1] + r3[1]);
        ov.z = (r0[2] + r1[2]) + (r2[2] + r3[2]);
        ov.w = (r0[3] + r1[3]) + (r2[3] + r3[3]);
        int pidx = head * KSPLIT + kp;
        *(float4*)&opart[((size_t)pidx * NN + i0 + q) * DH + d0] = ov;
        if (t < 32) {
            mpart[pidx * NN + i0 + t] = marr[t];
            lpart[pidx * NN + i0 + t] = larr[t];
        }
    }
}

// ---------------- attention merge + out_proj + atomic pool accumulate
__global__ __launch_bounds__(128) void k_mergeproj(const float* __restrict__ opart,
        const float* __restrict__ mpart, const float* __restrict__ lpart,
        const float* __restrict__ Wt_out, const float* __restrict__ bias,
        float* __restrict__ pp) {
    __shared__ float s[H];
    int row = blockIdx.x, t = threadIdx.x;
    int head = t >> 5, d = t & 31;
    float mv[KSPLIT];
    float M = -1e30f;
    #pragma unroll
    for (int p = 0; p < KSPLIT; ++p) {
        mv[p] = mpart[(head * KSPLIT + p) * NN + row];
        M = fmaxf(M, mv[p]);
    }
    float L = 0.f, o = 0.f;
    #pragma unroll
    for (int p = 0; p < KSPLIT; ++p) {
        float w = __expf(mv[p] - M);
        L = fmaf(lpart[(head * KSPLIT + p) * NN + row], w, L);
        o = fmaf(opart[((size_t)(head * KSPLIT + p) * NN + row) * DH + d], w, o);
    }
    s[t] = o / L;
    __syncthreads();
    float acc = bias[t];
    #pragma unroll 8
    for (int k = 0; k < H; ++k) acc = fmaf(s[k], Wt_out[k * H + t], acc);
    atomicAdd(&pp[(row & 31) * H + t], acc);
}

// ---------------- final pool + head
__global__ void k_poolhead(const float* __restrict__ pp, const float* __restrict__ outW,
        const float* __restrict__ outB, float* __restrict__ out) {
    __shared__ float pooled[H];
    int t = threadIdx.x;
    float s = 0.f;
    #pragma unroll 8
    for (int p = 0; p < 32; ++p) s += pp[p * H + t];
    pooled[t] = s * (1.f / 1024.f);
    __syncthreads();
    if (t < 6) {
        float acc = outB[t];
        for (int c = 0; c < H; ++c) acc = fmaf(pooled[c], outW[c * 6 + t], acc);
        out[t] = (t == 1) ? fmaxf(acc, 0.f) : 1.f / (1.f + expf(-acc));
    }
}

extern "C" void kernel_launch(void* const* d_in, const int* in_sizes, int n_in,
                              void* d_out, int out_size, void* d_ws, size_t ws_size,
                              hipStream_t stream) {
    const float* x       = (const float*)d_in[0];
    const float* emb_W   = (const float*)d_in[1];
    const float* emb_b   = (const float*)d_in[2];
    const float* ln_g    = (const float*)d_in[3];
    const float* ln_b    = (const float*)d_in[4];
    const float* edge_W1 = (const float*)d_in[5];
    const float* edge_b1 = (const float*)d_in[6];
    const float* edge_W2 = (const float*)d_in[7];
    const float* edge_b2 = (const float*)d_in[8];
    const float* gc_W    = (const float*)d_in[9];
    const float* gc_b    = (const float*)d_in[10];
    const float* in_proj_W  = (const float*)d_in[11];
    const float* in_proj_b  = (const float*)d_in[12];
    const float* out_proj_W = (const float*)d_in[13];
    const float* out_proj_b = (const float*)d_in[14];
    const float* out_W   = (const float*)d_in[15];
    const float* out_b   = (const float*)d_in[16];
    float* out = (float*)d_out;

    float* ws = (float*)d_ws;
    float* aM      = ws;                      // 131072
    float* bM      = aM + NN * H;             // 131072
    float* adj     = bM + NN * H;             // 1048576
    float* g       = adj + (size_t)NN * NN;   // 131072
    float* g2      = g + NN * H;              // 131072
    float* qkv     = g2 + NN * H;             // 393216
    float* Wt_in   = qkv + (size_t)NN * 384;  // 49152
    float* Wt_out  = Wt_in + 128 * 384;       // 16384
    float* pp      = Wt_out + 128 * 128;      // 4096
    // aliases (lifetimes disjoint):
    float* opart = adj;          // adj dead after k_gc384
    float* mpart = aM;           // aM/bM dead after k_adj
    float* lpart = aM + 32 * NN;

    k_embed<<<NN, 128, 0, stream>>>(x, emb_W, emb_b, ln_g, ln_b, edge_W1, edge_b1,
                                    gc_W, in_proj_W, out_proj_W, Wt_in, Wt_out,
                                    aM, bM, g);
    k_adj<<<dim3(NN / AT, NN / AT), 256, 0, stream>>>(aM, bM, edge_W2, edge_b2, adj);

    k_gc128<<<NN / 4, 512, 0, stream>>>(adj, g,  gc_b + 0 * H, gc_W + (size_t)1 * H * H, g2);
    k_gc128<<<NN / 4, 512, 0, stream>>>(adj, g2, gc_b + 1 * H, gc_W + (size_t)2 * H * H, g);
    k_gc128<<<NN / 4, 512, 0, stream>>>(adj, g,  gc_b + 2 * H, gc_W + (size_t)3 * H * H, g2);
    k_gc384<<<NN / 4, 512, 0, stream>>>(adj, g2, gc_b + 3 * H, Wt_in, in_proj_b, qkv);

    k_attn_part<<<dim3(NN / 32, HEADS, KSPLIT), 256, 0, stream>>>(qkv, opart, mpart, lpart, pp);
    k_mergeproj<<<NN, 128, 0, stream>>>(opart, mpart, lpart, Wt_out, out_proj_b, pp);
    k_poolhead<<<1, 128, 0, stream>>>(pp, out_W, out_b, out);
}

// Round 11
// 160.966 us; speedup vs baseline: 1.2640x; 1.2640x over previous
//
#include <hip/hip_runtime.h>
#include <math.h>

#define NN 1024
#define IN_DIM 64
#define H 128
#define NL 4
#define HEADS 4
#define DH 32
#define KSPLIT 8   // attention j-chunks of 128
#define RT 8
#define JC 256

// ---------------- embed: h=relu(LN(x@embW+b)); aM=h@W1a+eb1; bM=h@W1b; g0=h@gcW0
// + in_proj/out_proj transposes as side work (R10 verbatim)
__global__ __launch_bounds__(128) void k_embed(const float* __restrict__ x,
        const float* __restrict__ embW, const float* __restrict__ embB,
        const float* __restrict__ lng, const float* __restrict__ lnb,
        const float* __restrict__ eW1, const float* __restrict__ eb1,
        const float* __restrict__ gcW0,
        const float* __restrict__ inW, const float* __restrict__ outW,
        float* __restrict__ Wt_in, float* __restrict__ Wt_out,
        float* __restrict__ aM, float* __restrict__ bM, float* __restrict__ g0) {
    __shared__ float xs[IN_DIM];
    __shared__ float hs[H];
    __shared__ float red[H];
    int i = blockIdx.x, t = threadIdx.x;
    int gidx = i * 128 + t;
    if (gidx < 49152) {
        Wt_in[gidx] = inW[(gidx % 384) * 128 + gidx / 384];
    } else if (gidx < 65536) {
        int i2 = gidx - 49152;
        Wt_out[i2] = outW[(i2 % 128) * 128 + i2 / 128];
    }
    if (t < IN_DIM) xs[t] = x[i * IN_DIM + t];
    __syncthreads();
    float acc = embB[t];
    #pragma unroll 8
    for (int k = 0; k < IN_DIM; ++k) acc = fmaf(xs[k], embW[k * H + t], acc);
    red[t] = acc; __syncthreads();
    for (int s = 64; s > 0; s >>= 1) { if (t < s) red[t] += red[t + s]; __syncthreads(); }
    float mu = red[0] * (1.f / H);
    __syncthreads();
    float d = acc - mu;
    red[t] = d * d; __syncthreads();
    for (int s = 64; s > 0; s >>= 1) { if (t < s) red[t] += red[t + s]; __syncthreads(); }
    float var = red[0] * (1.f / H);
    float hv = d * rsqrtf(var + 1e-5f) * lng[t] + lnb[t];
    hv = fmaxf(hv, 0.f);
    hs[t] = hv;
    __syncthreads();
    float aa = eb1[t], bb = 0.f, gg = 0.f;
    #pragma unroll 8
    for (int k = 0; k < H; ++k) {
        float hk = hs[k];
        aa = fmaf(hk, eW1[k * H + t], aa);
        bb = fmaf(hk, eW1[(H + k) * H + t], bb);
        gg = fmaf(hk, gcW0[k * H + t], gg);
    }
    aM[i * H + t] = aa;
    bM[i * H + t] = bb;
    g0[i * H + t] = gg;
}

// ---------------- adj: 32x32 tile, b transposed in LDS, float4 inner (R3/R10 verbatim)
#define AT 32
__global__ __launch_bounds__(256) void k_adj(const float* __restrict__ aM, const float* __restrict__ bM,
        const float* __restrict__ w2, const float* __restrict__ eb2p, float* __restrict__ adj) {
    __shared__ float as_[AT][H + 4];
    __shared__ float bst[H][AT + 4];
    __shared__ float w2s[H];
    int i0 = blockIdx.y * AT, j0 = blockIdx.x * AT;
    int t = threadIdx.x;
    for (int idx = t; idx < AT * H; idx += 256) {
        int r = idx >> 7, c = idx & 127;
        as_[r][c] = aM[(i0 + r) * H + c];
        bst[c][r] = bM[(j0 + r) * H + c];
    }
    if (t < H) w2s[t] = w2[t];
    __syncthreads();
    int ti = t >> 3, tjg = t & 7;
    float a0 = 0.f, a1 = 0.f, a2 = 0.f, a3 = 0.f;
    const float eb2 = eb2p[0];
    #pragma unroll 4
    for (int h = 0; h < H; ++h) {
        float av = as_[ti][h];
        float4 bv = *(const float4*)&bst[h][tjg * 4];
        float wh = w2s[h];
        a0 = fmaf(fmaxf(av + bv.x, 0.f), wh, a0);
        a1 = fmaf(fmaxf(av + bv.y, 0.f), wh, a1);
        a2 = fmaf(fmaxf(av + bv.z, 0.f), wh, a2);
        a3 = fmaf(fmaxf(av + bv.w, 0.f), wh, a3);
    }
    int i = i0 + ti, jb = j0 + tjg * 4;
    float4 ov;
    ov.x = (i == jb + 0) ? 0.f : 1.f / (1.f + __expf(-(a0 + eb2)));
    ov.y = (i == jb + 1) ? 0.f : 1.f / (1.f + __expf(-(a1 + eb2)));
    ov.z = (i == jb + 2) ? 0.f : 1.f / (1.f + __expf(-(a2 + eb2)));
    ov.w = (i == jb + 3) ? 0.f : 1.f / (1.f + __expf(-(a3 + eb2)));
    *(float4*)&adj[(size_t)i * NN + jb] = ov;
}

// ---------------- spmm (round-1 structure, float4 g loads):
// partial[p][i][c] = sum_{j in 256-chunk p} adj[i][j]*g[j][c]; grid (128,4) x 256 thr
__global__ __launch_bounds__(256) void k_spmm(const float* __restrict__ adj, const float* __restrict__ g,
        float* __restrict__ partial) {
    __shared__ float adjs[RT][JC];          // 8 KB
    __shared__ float redbuf[RT][H];         // 4 KB
    int rt = blockIdx.x;   // 0..127
    int p = blockIdx.y;    // 0..3
    int t = threadIdx.x;
    int r0 = rt * RT;
    #pragma unroll
    for (int it = 0; it < 2; ++it) {
        int idx = t + it * 256;              // [0,512): 64 float4 per row
        int r = idx >> 6, jf = idx & 63;
        float4 v = *(const float4*)&adj[(size_t)(r0 + r) * NN + p * JC + jf * 4];
        adjs[r][jf * 4 + 0] = v.x; adjs[r][jf * 4 + 1] = v.y;
        adjs[r][jf * 4 + 2] = v.z; adjs[r][jf * 4 + 3] = v.w;
    }
    __syncthreads();
    int cg = t & 31, half = (t >> 5) & 1, rg = t >> 6;   // 4 rowgroups x 2 halves x 32 colgroups
    int c0 = cg * 4;
    int jbase = half * 128;
    int ra = rg * 2, rb = rg * 2 + 1;
    float acc0[4] = {}, acc1[4] = {};
    #pragma unroll 4
    for (int jj = 0; jj < 128; ++jj) {
        int ja = jbase + jj;
        float4 gv = *(const float4*)&g[(p * JC + ja) * H + c0];
        float a0 = adjs[ra][ja], a1 = adjs[rb][ja];
        acc0[0] = fmaf(a0, gv.x, acc0[0]); acc0[1] = fmaf(a0, gv.y, acc0[1]);
        acc0[2] = fmaf(a0, gv.z, acc0[2]); acc0[3] = fmaf(a0, gv.w, acc0[3]);
        acc1[0] = fmaf(a1, gv.x, acc1[0]); acc1[1] = fmaf(a1, gv.y, acc1[1]);
        acc1[2] = fmaf(a1, gv.z, acc1[2]); acc1[3] = fmaf(a1, gv.w, acc1[3]);
    }
    if (half == 1) {
        *(float4*)&redbuf[ra][c0] = *(float4*)acc0;
        *(float4*)&redbuf[rb][c0] = *(float4*)acc1;
    }
    __syncthreads();
    if (half == 0) {
        float4 r0v = *(float4*)&redbuf[ra][c0];
        float4 r1v = *(float4*)&redbuf[rb][c0];
        float4 o0 = {acc0[0] + r0v.x, acc0[1] + r0v.y, acc0[2] + r0v.z, acc0[3] + r0v.w};
        float4 o1 = {acc1[0] + r1v.x, acc1[1] + r1v.y, acc1[2] + r1v.z, acc1[3] + r1v.w};
        *(float4*)&partial[((size_t)p * NN + r0 + ra) * H + c0] = o0;
        *(float4*)&partial[((size_t)p * NN + r0 + rb) * H + c0] = o1;
    }
}

// ---------------- fused 4-way reduce + bias + next matmul (round-1 verbatim)
__global__ __launch_bounds__(128) void k_redmat128(const float* __restrict__ partial,
        const float* __restrict__ bias, const float* __restrict__ W, float* __restrict__ outM) {
    __shared__ float s[H];
    int i = blockIdx.x, t = threadIdx.x;
    float v = partial[i * H + t] + partial[NN * H + i * H + t]
            + partial[2 * NN * H + i * H + t] + partial[3 * NN * H + i * H + t] + bias[t];
    s[t] = v;
    __syncthreads();
    float acc = 0.f;
    #pragma unroll 8
    for (int k = 0; k < H; ++k) acc = fmaf(s[k], W[k * H + t], acc);
    outM[i * H + t] = acc;
}

__global__ __launch_bounds__(384) void k_redmat384(const float* __restrict__ partial,
        const float* __restrict__ bias, const float* __restrict__ W,
        const float* __restrict__ bias2, float* __restrict__ outM) {
    __shared__ float s[H];
    int i = blockIdx.x, t = threadIdx.x;
    if (t < H) {
        float v = partial[i * H + t] + partial[NN * H + i * H + t]
                + partial[2 * NN * H + i * H + t] + partial[3 * NN * H + i * H + t] + bias[t];
        s[t] = v;
    }
    __syncthreads();
    float acc = bias2[t];
    #pragma unroll 8
    for (int k = 0; k < H; ++k) acc = fmaf(s[k], W[k * 384 + t], acc);
    outM[i * 384 + t] = acc;
}

// ---------------- split-K attention (R10 verbatim, incl. pp zeroing side-task)
__global__ __launch_bounds__(256) void k_attn_part(const float* __restrict__ qkv,
        float* __restrict__ opart, float* __restrict__ mpart, float* __restrict__ lpart,
        float* __restrict__ pp) {
    __shared__ float kob[4][32][36];
    __shared__ float qT[32][36];
    __shared__ float pT[128][36];
    __shared__ float marr[32], larr[32];
    float* kT = &kob[0][0][0];
    const int t = threadIdx.x;
    const int head = blockIdx.y, kp = blockIdx.z;
    const int i0 = blockIdx.x * 32, j0 = kp * 128;
    const int qoff = head * DH, koff = H + head * DH, voff = 2 * H + head * DH;
    const float scale = 0.17677669529663687f; // 1/sqrt(32)
    if (head == 0 && kp == 0 && t < 128) pp[blockIdx.x * 128 + t] = 0.f;
    {
        int qi = t >> 3, dg = t & 7;
        float4 qv = *(const float4*)&qkv[(i0 + qi) * 384 + qoff + dg * 4];
        qT[dg * 4 + 0][qi] = qv.x * scale;
        qT[dg * 4 + 1][qi] = qv.y * scale;
        qT[dg * 4 + 2][qi] = qv.z * scale;
        qT[dg * 4 + 3][qi] = qv.w * scale;
    }
    #pragma unroll
    for (int it = 0; it < 4; ++it) {
        int idx = t + it * 256;
        int j = idx >> 3, dg = idx & 7;
        float4 kv = *(const float4*)&qkv[(j0 + j) * 384 + koff + dg * 4];
        kT[(dg * 4 + 0) * 132 + j] = kv.x;
        kT[(dg * 4 + 1) * 132 + j] = kv.y;
        kT[(dg * 4 + 2) * 132 + j] = kv.z;
        kT[(dg * 4 + 3) * 132 + j] = kv.w;
    }
    __syncthreads();
    const int tq = t >> 5, tj = t & 31;
    float s[4][4] = {};
    #pragma unroll
    for (int kk = 0; kk < DH; ++kk) {
        float qa[4], ka[4];
        *(float4*)qa = *(float4*)&qT[kk][tq * 4];
        *(float4*)ka = *(float4*)&kT[kk * 132 + tj * 4];
        #pragma unroll
        for (int a = 0; a < 4; ++a)
            #pragma unroll
            for (int b = 0; b < 4; ++b) s[a][b] = fmaf(qa[a], ka[b], s[a][b]);
    }
    #pragma unroll
    for (int a = 0; a < 4; ++a) {
        float mm = fmaxf(fmaxf(s[a][0], s[a][1]), fmaxf(s[a][2], s[a][3]));
        #pragma unroll
        for (int off = 16; off > 0; off >>= 1) mm = fmaxf(mm, __shfl_xor(mm, off));
        float ll = 0.f;
        #pragma unroll
        for (int b = 0; b < 4; ++b) { s[a][b] = __expf(s[a][b] - mm); ll += s[a][b]; }
        #pragma unroll
        for (int off = 16; off > 0; off >>= 1) ll += __shfl_xor(ll, off);
        if (tj == 0) { marr[tq * 4 + a] = mm; larr[tq * 4 + a] = ll; }
    }
    #pragma unroll
    for (int b = 0; b < 4; ++b)
        #pragma unroll
        for (int a = 0; a < 4; ++a) pT[tj * 4 + b][tq * 4 + a] = s[a][b];
    __syncthreads();
    const int qg = t >> 5, dg2 = (t >> 2) & 7, st = t & 3;
    float o[4][4] = {};
    #pragma unroll 4
    for (int jj = 0; jj < 32; ++jj) {
        int j = st * 32 + jj;
        float pa[4], va[4];
        *(float4*)pa = *(float4*)&pT[j][qg * 4];
        *(float4*)va = *(const float4*)&qkv[(j0 + j) * 384 + voff + dg2 * 4];
        #pragma unroll
        for (int a = 0; a < 4; ++a)
            #pragma unroll
            for (int b = 0; b < 4; ++b) o[a][b] = fmaf(pa[a], va[b], o[a][b]);
    }
    __syncthreads();
    #pragma unroll
    for (int a = 0; a < 4; ++a)
        #pragma unroll
        for (int b = 0; b < 4; ++b) kob[st][qg * 4 + a][dg2 * 4 + b] = o[a][b];
    __syncthreads();
    {
        int q = t >> 3, d0 = (t & 7) * 4;
        float r0[4], r1[4], r2[4], r3[4];
        *(float4*)r0 = *(float4*)&kob[0][q][d0];
        *(float4*)r1 = *(float4*)&kob[1][q][d0];
        *(float4*)r2 = *(float4*)&kob[2][q][d0];
        *(float4*)r3 = *(float4*)&kob[3][q][d0];
        float4 ov;
        ov.x = (r0[0] + r1[0]) + (r2[0] + r3[0]);
        ov.y = (r0[1] + r1[1]) + (r2[1] + r3[1]);
        ov.z = (r0[2] + r1[2]) + (r2[2] + r3[2]);
        ov.w = (r0[3] + r1[3]) + (r2[3] + r3[3]);
        int pidx = head * KSPLIT + kp;
        *(float4*)&opart[((size_t)pidx * NN + i0 + q) * DH + d0] = ov;
        if (t < 32) {
            mpart[pidx * NN + i0 + t] = marr[t];
            lpart[pidx * NN + i0 + t] = larr[t];
        }
    }
}

// ---------------- attention merge + out_proj + atomic pool accumulate (R10 verbatim)
__global__ __launch_bounds__(128) void k_mergeproj(const float* __restrict__ opart,
        const float* __restrict__ mpart, const float* __restrict__ lpart,
        const float* __restrict__ Wt_out, const float* __restrict__ bias,
        float* __restrict__ pp) {
    __shared__ float s[H];
    int row = blockIdx.x, t = threadIdx.x;
    int head = t >> 5, d = t & 31;
    float mv[KSPLIT];
    float M = -1e30f;
    #pragma unroll
    for (int p = 0; p < KSPLIT; ++p) {
        mv[p] = mpart[(head * KSPLIT + p) * NN + row];
        M = fmaxf(M, mv[p]);
    }
    float L = 0.f, o = 0.f;
    #pragma unroll
    for (int p = 0; p < KSPLIT; ++p) {
        float w = __expf(mv[p] - M);
        L = fmaf(lpart[(head * KSPLIT + p) * NN + row], w, L);
        o = fmaf(opart[((size_t)(head * KSPLIT + p) * NN + row) * DH + d], w, o);
    }
    s[t] = o / L;
    __syncthreads();
    float acc = bias[t];
    #pragma unroll 8
    for (int k = 0; k < H; ++k) acc = fmaf(s[k], Wt_out[k * H + t], acc);
    atomicAdd(&pp[(row & 31) * H + t], acc);
}

// ---------------- final pool + head (R10 verbatim)
__global__ void k_poolhead(const float* __restrict__ pp, const float* __restrict__ outW,
        const float* __restrict__ outB, float* __restrict__ out) {
    __shared__ float pooled[H];
    int t = threadIdx.x;
    float s = 0.f;
    #pragma unroll 8
    for (int p = 0; p < 32; ++p) s += pp[p * H + t];
    pooled[t] = s * (1.f / 1024.f);
    __syncthreads();
    if (t < 6) {
        float acc = outB[t];
        for (int c = 0; c < H; ++c) acc = fmaf(pooled[c], outW[c * 6 + t], acc);
        out[t] = (t == 1) ? fmaxf(acc, 0.f) : 1.f / (1.f + expf(-acc));
    }
}

extern "C" void kernel_launch(void* const* d_in, const int* in_sizes, int n_in,
                              void* d_out, int out_size, void* d_ws, size_t ws_size,
                              hipStream_t stream) {
    const float* x       = (const float*)d_in[0];
    const float* emb_W   = (const float*)d_in[1];
    const float* emb_b   = (const float*)d_in[2];
    const float* ln_g    = (const float*)d_in[3];
    const float* ln_b    = (const float*)d_in[4];
    const float* edge_W1 = (const float*)d_in[5];
    const float* edge_b1 = (const float*)d_in[6];
    const float* edge_W2 = (const float*)d_in[7];
    const float* edge_b2 = (const float*)d_in[8];
    const float* gc_W    = (const float*)d_in[9];
    const float* gc_b    = (const float*)d_in[10];
    const float* in_proj_W  = (const float*)d_in[11];
    const float* in_proj_b  = (const float*)d_in[12];
    const float* out_proj_W = (const float*)d_in[13];
    const float* out_proj_b = (const float*)d_in[14];
    const float* out_W   = (const float*)d_in[15];
    const float* out_b   = (const float*)d_in[16];
    float* out = (float*)d_out;

    float* ws = (float*)d_ws;
    float* aM      = ws;                      // 131072
    float* bM      = aM + NN * H;             // 131072
    float* adj     = bM + NN * H;             // 1048576
    float* g       = adj + (size_t)NN * NN;   // 131072
    float* partial = g + NN * H;              // 4*131072 = 524288
    float* qkv     = partial + (size_t)4 * NN * H;  // 393216
    float* Wt_in   = qkv + (size_t)NN * 384;  // 49152
    float* Wt_out  = Wt_in + 128 * 384;       // 16384
    float* pp      = Wt_out + 128 * 128;      // 4096
    // aliases (lifetimes disjoint):
    float* opart = adj;          // 32*1024*32 = 1048576, adj dead after last spmm
    float* mpart = aM;           // aM/bM dead after k_adj
    float* lpart = aM + 32 * NN;

    k_embed<<<NN, 128, 0, stream>>>(x, emb_W, emb_b, ln_g, ln_b, edge_W1, edge_b1,
                                    gc_W, in_proj_W, out_proj_W, Wt_in, Wt_out,
                                    aM, bM, g);
    k_adj<<<dim3(NN / AT, NN / AT), 256, 0, stream>>>(aM, bM, edge_W2, edge_b2, adj);

    for (int l = 0; l < NL; ++l) {
        k_spmm<<<dim3(NN / RT, 4), 256, 0, stream>>>(adj, g, partial);
        if (l < NL - 1)
            k_redmat128<<<NN, 128, 0, stream>>>(partial, gc_b + (size_t)l * H,
                                                gc_W + (size_t)(l + 1) * H * H, g);
        else
            k_redmat384<<<NN, 384, 0, stream>>>(partial, gc_b + (size_t)l * H,
                                                Wt_in, in_proj_b, qkv);
    }

    k_attn_part<<<dim3(NN / 32, HEADS, KSPLIT), 256, 0, stream>>>(qkv, opart, mpart, lpart, pp);
    k_mergeproj<<<NN, 128, 0, stream>>>(opart, mpart, lpart, Wt_out, out_proj_b, pp);
    k_poolhead<<<1, 128, 0, stream>>>(pp, out_W, out_b, out);
}